// Round 14
// baseline (184.443 us; speedup 1.0000x reference)
//
#include <hip/hip_runtime.h>
#include <hip/hip_cooperative_groups.h>

// SemanticConditioner: out = canvas + (embeddings @ W^T + residuals)[region_ids]
// B=4, N=65536, D=256, E=1536, R=512  (all fp32)

#define B_DIM 4
#define N_DIM 65536
#define D_DIM 256
#define E_DIM 1536
#define R_DIM 512
#define RPB   8     // embedding rows per block (cond GEMM)
#define KS    8     // K-splits (cond GEMM)
#define KSUB  (E_DIM / KS)      // 192
#define KSUB4 (KSUB / 4)        // 48

typedef float f32x4 __attribute__((ext_vector_type(4)));

// ---------------------------------------------------------------------------
// Kernel 1 (cooperative): fused cond GEMM + reduce.
// Phase 1: part[ks][r][d] = sum_{e in ks-chunk} emb[r][e] * W[d][e]
//   (W read directly: thread d reads its OWN contiguous W-row chunk as
//    float4 — W[d][e..e+3]; 75% L1 hits, active set 16 KB << 32 KB L1.)
// grid.sync()
// Phase 2: cond[i] = sum_ks part[ks][i] + res[i], one element per thread
//   (512 blocks x 256 threads = 131072 = R*D exactly; part rows L2-hot).
// grid 512 blocks (bid>>6 = ks, bid&63 = r-block) = 2 blocks/CU co-resident.
// ---------------------------------------------------------------------------
__global__ __launch_bounds__(256) void k_cond_coop(const float* __restrict__ emb,
                                                   const float* __restrict__ W,
                                                   const float* __restrict__ res,
                                                   float* __restrict__ part,
                                                   float* __restrict__ cond) {
    __shared__ f32x4 embs[RPB][KSUB4];  // 6 KB
    const int bid = blockIdx.x;
    const int ks  = bid >> 6;           // 0..7
    const int r0  = (bid & 63) * RPB;
    const int d   = threadIdx.x;

    const f32x4* eg = reinterpret_cast<const f32x4*>(emb);
    for (int f = d; f < RPB * KSUB4; f += 256) {
        const int rr = f / KSUB4, gg = f % KSUB4;
        embs[rr][gg] = eg[(size_t)(r0 + rr) * (E_DIM / 4) + ks * KSUB4 + gg];
    }
    __syncthreads();

    float a0 = 0.f, a1 = 0.f, a2 = 0.f, a3 = 0.f;
    float a4 = 0.f, a5 = 0.f, a6 = 0.f, a7 = 0.f;
    // thread's own W-row chunk: W[d][ks*KSUB .. +KSUB), contiguous
    const f32x4* wrow =
        reinterpret_cast<const f32x4*>(W + (size_t)d * E_DIM + ks * KSUB);
#pragma unroll 4
    for (int g = 0; g < KSUB4; ++g) {
        const f32x4 w = wrow[g];
        const float w0 = w.x, w1 = w.y, w2 = w.z, w3 = w.w;
        { const f32x4 v = embs[0][g]; a0 += v.x*w0 + v.y*w1 + v.z*w2 + v.w*w3; }
        { const f32x4 v = embs[1][g]; a1 += v.x*w0 + v.y*w1 + v.z*w2 + v.w*w3; }
        { const f32x4 v = embs[2][g]; a2 += v.x*w0 + v.y*w1 + v.z*w2 + v.w*w3; }
        { const f32x4 v = embs[3][g]; a3 += v.x*w0 + v.y*w1 + v.z*w2 + v.w*w3; }
        { const f32x4 v = embs[4][g]; a4 += v.x*w0 + v.y*w1 + v.z*w2 + v.w*w3; }
        { const f32x4 v = embs[5][g]; a5 += v.x*w0 + v.y*w1 + v.z*w2 + v.w*w3; }
        { const f32x4 v = embs[6][g]; a6 += v.x*w0 + v.y*w1 + v.z*w2 + v.w*w3; }
        { const f32x4 v = embs[7][g]; a7 += v.x*w0 + v.y*w1 + v.z*w2 + v.w*w3; }
    }
    float* p = part + ((size_t)ks * R_DIM + r0) * D_DIM + d;
    p[0 * D_DIM] = a0;
    p[1 * D_DIM] = a1;
    p[2 * D_DIM] = a2;
    p[3 * D_DIM] = a3;
    p[4 * D_DIM] = a4;
    p[5 * D_DIM] = a5;
    p[6 * D_DIM] = a6;
    p[7 * D_DIM] = a7;

    // ---- grid-wide barrier, then reduce (one element per thread) ----
    cooperative_groups::this_grid().sync();

    const int i = bid * 256 + d;        // 0 .. R*D-1 exactly
    const size_t stride = (size_t)R_DIM * D_DIM;
    float s = res[i];
#pragma unroll
    for (int k = 0; k < KS; ++k)
        s += part[i + k * stride];
    cond[i] = s;
}

// ---------------------------------------------------------------------------
// Kernel 2: out = canvas + cond[region_ids]   — EXACT R11/R13 winner
// 16384 blocks, one thread = one d4 across all B=4 batch rows (b-fused:
// 1 rid + 1 cond gather serve 4 canvas/out row triples).
// Cached canvas loads (L3 absorbs ~47% of reads) + NT stores (no-allocate).
// Block pool 16384 is the measured optimum (2048<8192<16384>65536).
// ---------------------------------------------------------------------------
__global__ __launch_bounds__(256) void k_add(const f32x4* __restrict__ canvas,
                                             const int* __restrict__ rid,
                                             const f32x4* __restrict__ cond,
                                             f32x4* __restrict__ out) {
    const int bstep = N_DIM * (D_DIM / 4);                  // 4,194,304 float4
    const int i = blockIdx.x * blockDim.x + threadIdx.x;    // n*64 + d4
    const f32x4 c0 = canvas[i];
    const f32x4 c1 = canvas[i + bstep];
    const f32x4 c2 = canvas[i + 2 * bstep];
    const f32x4 c3 = canvas[i + 3 * bstep];
    const int n  = i >> 6;              // wave-uniform
    const int d4 = i & 63;
    const int r  = rid[n];              // wave-uniform, L1/L2
    const f32x4 a = cond[r * (D_DIM / 4) + d4];  // coalesced 1 KB row, L2
    __builtin_nontemporal_store(c0 + a, &out[i]);
    __builtin_nontemporal_store(c1 + a, &out[i + bstep]);
    __builtin_nontemporal_store(c2 + a, &out[i + 2 * bstep]);
    __builtin_nontemporal_store(c3 + a, &out[i + 3 * bstep]);
}

// ---------------------------------------------------------------------------
extern "C" void kernel_launch(void* const* d_in, const int* in_sizes, int n_in,
                              void* d_out, int out_size, void* d_ws, size_t ws_size,
                              hipStream_t stream) {
    const float* canvas = (const float*)d_in[0];  // [B,N,D]
    const float* emb    = (const float*)d_in[1];  // [R,E]
    const float* W      = (const float*)d_in[2];  // [D,E]
    const float* res    = (const float*)d_in[3];  // [R,D]
    const int*   rid    = (const int*)d_in[4];    // [N]

    // ws layout: part (KS*R*D fp32 = 4 MB) | cond (R*D fp32 = 0.5 MB)
    float* part = (float*)d_ws;
    float* cond = part + (size_t)KS * R_DIM * D_DIM;

    void* cargs[] = {(void*)&emb, (void*)&W, (void*)&res,
                     (void*)&part, (void*)&cond};
    hipLaunchCooperativeKernel(reinterpret_cast<void*>(k_cond_coop),
                               dim3(512), dim3(256), cargs, 0, stream);
    k_add<<<16384, 256, 0, stream>>>((const f32x4*)canvas, rid,
                                     (const f32x4*)cond, (f32x4*)d_out);
}

// Round 15
// 112.854 us; speedup vs baseline: 1.6344x; 1.6344x over previous
//
#include <hip/hip_runtime.h>

// SemanticConditioner: out = canvas + (embeddings @ W^T + residuals)[region_ids]
// B=4, N=65536, D=256, E=1536, R=512  (all fp32)

#define B_DIM 4
#define N_DIM 65536
#define D_DIM 256
#define E_DIM 1536
#define R_DIM 512
#define RPB   8     // embedding rows per block (cond GEMM)
#define KS    8     // K-splits (cond GEMM)
#define KSUB  (E_DIM / KS)      // 192
#define KSUB4 (KSUB / 4)        // 48

typedef float f32x4 __attribute__((ext_vector_type(4)));

// ---------------------------------------------------------------------------
// Kernel 1: partial GEMM, W read directly (thread d reads its own contiguous
// W-row chunk as float4; 75% L1 hits, active set 16 KB << 32 KB L1).
// part[ks][r][d] = sum_{e in ks-chunk} emb[r][e] * W[d][e]
// grid (R/RPB, KS) = (64, 8) = 512 blocks, 256 threads   [exact R13 kernel]
// ---------------------------------------------------------------------------
__global__ __launch_bounds__(256) void k_cond_direct(const float* __restrict__ emb,
                                                     const float* __restrict__ W,
                                                     float* __restrict__ part) {
    __shared__ f32x4 embs[RPB][KSUB4];  // 6 KB
    const int r0 = blockIdx.x * RPB;
    const int ks = blockIdx.y;
    const int d  = threadIdx.x;

    const f32x4* eg = reinterpret_cast<const f32x4*>(emb);
    for (int f = d; f < RPB * KSUB4; f += 256) {
        const int rr = f / KSUB4, gg = f % KSUB4;
        embs[rr][gg] = eg[(size_t)(r0 + rr) * (E_DIM / 4) + ks * KSUB4 + gg];
    }
    __syncthreads();

    float a0 = 0.f, a1 = 0.f, a2 = 0.f, a3 = 0.f;
    float a4 = 0.f, a5 = 0.f, a6 = 0.f, a7 = 0.f;
    const f32x4* wrow =
        reinterpret_cast<const f32x4*>(W + (size_t)d * E_DIM + ks * KSUB);
#pragma unroll 4
    for (int g = 0; g < KSUB4; ++g) {
        const f32x4 w = wrow[g];
        const float w0 = w.x, w1 = w.y, w2 = w.z, w3 = w.w;
        { const f32x4 v = embs[0][g]; a0 += v.x*w0 + v.y*w1 + v.z*w2 + v.w*w3; }
        { const f32x4 v = embs[1][g]; a1 += v.x*w0 + v.y*w1 + v.z*w2 + v.w*w3; }
        { const f32x4 v = embs[2][g]; a2 += v.x*w0 + v.y*w1 + v.z*w2 + v.w*w3; }
        { const f32x4 v = embs[3][g]; a3 += v.x*w0 + v.y*w1 + v.z*w2 + v.w*w3; }
        { const f32x4 v = embs[4][g]; a4 += v.x*w0 + v.y*w1 + v.z*w2 + v.w*w3; }
        { const f32x4 v = embs[5][g]; a5 += v.x*w0 + v.y*w1 + v.z*w2 + v.w*w3; }
        { const f32x4 v = embs[6][g]; a6 += v.x*w0 + v.y*w1 + v.z*w2 + v.w*w3; }
        { const f32x4 v = embs[7][g]; a7 += v.x*w0 + v.y*w1 + v.z*w2 + v.w*w3; }
    }
    float* p = part + ((size_t)ks * R_DIM + r0) * D_DIM + d;
    p[0 * D_DIM] = a0;
    p[1 * D_DIM] = a1;
    p[2 * D_DIM] = a2;
    p[3 * D_DIM] = a3;
    p[4 * D_DIM] = a4;
    p[5 * D_DIM] = a5;
    p[6 * D_DIM] = a6;
    p[7 * D_DIM] = a7;
}

// ---------------------------------------------------------------------------
// Kernel 2: cond[r][d] = sum_ks part[ks][r][d] + res[r][d]   [exact R13 kernel]
// grid R*D/256 = 512 blocks, 256 threads
// ---------------------------------------------------------------------------
__global__ __launch_bounds__(256) void k_reduce(const float* __restrict__ part,
                                                const float* __restrict__ res,
                                                float* __restrict__ cond) {
    const int i = blockIdx.x * 256 + threadIdx.x;  // r*D + d
    const size_t stride = (size_t)R_DIM * D_DIM;
    float s = res[i];
#pragma unroll
    for (int ks = 0; ks < KS; ++ks)
        s += part[i + ks * stride];
    cond[i] = s;
}

// ---------------------------------------------------------------------------
// Kernel 3: out = canvas + cond[region_ids]
// A/B this round (single variable vs R13): break the vmcnt in-order chain.
// vmcnt decrements in ISSUE order, so R13's order (4 canvas loads, then rid,
// then cond) forced vmcnt(0) — a full HBM drain — before the cond gather
// could even issue. Fix: n is wave-uniform -> readfirstlane makes rid[n] a
// SCALAR load on the lgkmcnt path (decoupled from vmcnt), issued FIRST;
// canvas loads fill its latency shadow; cond issues as soon as r lands.
// Dep chain: max(canvas_HBM, s_load+cond_L2) instead of their sum.
// Cached canvas loads (L3 absorbs ~47%) + NT stores (no-allocate).
// 16384 blocks (measured optimum), b-fused 4 rows per thread.
// ---------------------------------------------------------------------------
__global__ __launch_bounds__(256) void k_add(const f32x4* __restrict__ canvas,
                                             const int* __restrict__ rid,
                                             const f32x4* __restrict__ cond,
                                             f32x4* __restrict__ out) {
    const int bstep = N_DIM * (D_DIM / 4);                  // 4,194,304 float4
    const int i = blockIdx.x * blockDim.x + threadIdx.x;    // n*64 + d4
    // wave-uniform row index -> scalar register -> s_load on lgkmcnt path
    const int n = __builtin_amdgcn_readfirstlane(i >> 6);
    const int r = rid[n];               // s_load: issues first, off vmcnt
    const f32x4 c0 = canvas[i];
    const f32x4 c1 = canvas[i + bstep];
    const f32x4 c2 = canvas[i + 2 * bstep];
    const f32x4 c3 = canvas[i + 3 * bstep];
    const int d4 = i & 63;
    const f32x4 a = cond[r * (D_DIM / 4) + d4];  // SGPR base + lane offset, L2
    __builtin_nontemporal_store(c0 + a, &out[i]);
    __builtin_nontemporal_store(c1 + a, &out[i + bstep]);
    __builtin_nontemporal_store(c2 + a, &out[i + 2 * bstep]);
    __builtin_nontemporal_store(c3 + a, &out[i + 3 * bstep]);
}

// ---------------------------------------------------------------------------
extern "C" void kernel_launch(void* const* d_in, const int* in_sizes, int n_in,
                              void* d_out, int out_size, void* d_ws, size_t ws_size,
                              hipStream_t stream) {
    const float* canvas = (const float*)d_in[0];  // [B,N,D]
    const float* emb    = (const float*)d_in[1];  // [R,E]
    const float* W      = (const float*)d_in[2];  // [D,E]
    const float* res    = (const float*)d_in[3];  // [R,D]
    const int*   rid    = (const int*)d_in[4];    // [N]

    // ws layout: part (KS*R*D fp32 = 4 MB) | cond (R*D fp32 = 0.5 MB)
    float* part = (float*)d_ws;
    float* cond = part + (size_t)KS * R_DIM * D_DIM;

    dim3 cgrid(R_DIM / RPB, KS);
    k_cond_direct<<<cgrid, 256, 0, stream>>>(emb, W, part);
    k_reduce<<<(R_DIM * D_DIM) / 256, 256, 0, stream>>>(part, res, cond);
    k_add<<<16384, 256, 0, stream>>>((const f32x4*)canvas, rid,
                                     (const f32x4*)cond, (f32x4*)d_out);
}

// Round 16
// 110.352 us; speedup vs baseline: 1.6714x; 1.0227x over previous
//
#include <hip/hip_runtime.h>

// SemanticConditioner: out = canvas + (embeddings @ W^T + residuals)[region_ids]
// B=4, N=65536, D=256, E=1536, R=512  (all fp32)

#define B_DIM 4
#define N_DIM 65536
#define D_DIM 256
#define E_DIM 1536
#define R_DIM 512
#define RPB   8     // embedding rows per block (cond GEMM)
#define KS    8     // K-splits (cond GEMM)
#define KSUB  (E_DIM / KS)      // 192
#define KSUB4 (KSUB / 4)        // 48

typedef float f32x4 __attribute__((ext_vector_type(4)));

// ---------------------------------------------------------------------------
// Kernel 1: partial GEMM, W read directly (thread d reads its own contiguous
// W-row chunk as float4; 75% L1 hits, active set 16 KB << 32 KB L1).
// part[ks][r][d] = sum_{e in ks-chunk} emb[r][e] * W[d][e]
// grid (R/RPB, KS) = (64, 8) = 512 blocks, 256 threads   [exact R15 kernel]
// ---------------------------------------------------------------------------
__global__ __launch_bounds__(256) void k_cond_direct(const float* __restrict__ emb,
                                                     const float* __restrict__ W,
                                                     float* __restrict__ part) {
    __shared__ f32x4 embs[RPB][KSUB4];  // 6 KB
    const int r0 = blockIdx.x * RPB;
    const int ks = blockIdx.y;
    const int d  = threadIdx.x;

    const f32x4* eg = reinterpret_cast<const f32x4*>(emb);
    for (int f = d; f < RPB * KSUB4; f += 256) {
        const int rr = f / KSUB4, gg = f % KSUB4;
        embs[rr][gg] = eg[(size_t)(r0 + rr) * (E_DIM / 4) + ks * KSUB4 + gg];
    }
    __syncthreads();

    float a0 = 0.f, a1 = 0.f, a2 = 0.f, a3 = 0.f;
    float a4 = 0.f, a5 = 0.f, a6 = 0.f, a7 = 0.f;
    const f32x4* wrow =
        reinterpret_cast<const f32x4*>(W + (size_t)d * E_DIM + ks * KSUB);
#pragma unroll 4
    for (int g = 0; g < KSUB4; ++g) {
        const f32x4 w = wrow[g];
        const float w0 = w.x, w1 = w.y, w2 = w.z, w3 = w.w;
        { const f32x4 v = embs[0][g]; a0 += v.x*w0 + v.y*w1 + v.z*w2 + v.w*w3; }
        { const f32x4 v = embs[1][g]; a1 += v.x*w0 + v.y*w1 + v.z*w2 + v.w*w3; }
        { const f32x4 v = embs[2][g]; a2 += v.x*w0 + v.y*w1 + v.z*w2 + v.w*w3; }
        { const f32x4 v = embs[3][g]; a3 += v.x*w0 + v.y*w1 + v.z*w2 + v.w*w3; }
        { const f32x4 v = embs[4][g]; a4 += v.x*w0 + v.y*w1 + v.z*w2 + v.w*w3; }
        { const f32x4 v = embs[5][g]; a5 += v.x*w0 + v.y*w1 + v.z*w2 + v.w*w3; }
        { const f32x4 v = embs[6][g]; a6 += v.x*w0 + v.y*w1 + v.z*w2 + v.w*w3; }
        { const f32x4 v = embs[7][g]; a7 += v.x*w0 + v.y*w1 + v.z*w2 + v.w*w3; }
    }
    float* p = part + ((size_t)ks * R_DIM + r0) * D_DIM + d;
    p[0 * D_DIM] = a0;
    p[1 * D_DIM] = a1;
    p[2 * D_DIM] = a2;
    p[3 * D_DIM] = a3;
    p[4 * D_DIM] = a4;
    p[5 * D_DIM] = a5;
    p[6 * D_DIM] = a6;
    p[7 * D_DIM] = a7;
}

// ---------------------------------------------------------------------------
// Kernel 2: cond[r][d] = sum_ks part[ks][r][d] + res[r][d]   [exact R15 kernel]
// grid R*D/256 = 512 blocks, 256 threads
// ---------------------------------------------------------------------------
__global__ __launch_bounds__(256) void k_reduce(const float* __restrict__ part,
                                                const float* __restrict__ res,
                                                float* __restrict__ cond) {
    const int i = blockIdx.x * 256 + threadIdx.x;  // r*D + d
    const size_t stride = (size_t)R_DIM * D_DIM;
    float s = res[i];
#pragma unroll
    for (int ks = 0; ks < KS; ++ks)
        s += part[i + ks * stride];
    cond[i] = s;
}

// ---------------------------------------------------------------------------
// Kernel 3: out = canvas + cond[region_ids]
// A/B this round (single variable vs R15): FLIP the L3 allocation policy.
// R7-R15 counters (FETCH 140 / WRITE 262 MB steady-state) prove NT stores
// still allocate out-lines in L3 (else canvas would own L3 and FETCH ~20 MB).
// out (256 MB) alone exactly fits the 256 MB memory-side L3 and is fully
// OVERWRITTEN each replay -> if out is the sole allocator, replays overwrite
// dirty lines IN L3 and HBM write traffic collapses. So: NT loads for canvas
// (no-allocate, cede L3 to out) + plain cached stores for out (allocate).
// Signature if right: WRITE_SIZE 262 -> <100 MB, FETCH 140 -> ~260 MB.
// rid scalar path + 16384 blocks + b-fusion unchanged (R15 winner).
// ---------------------------------------------------------------------------
__global__ __launch_bounds__(256) void k_add(const f32x4* __restrict__ canvas,
                                             const int* __restrict__ rid,
                                             const f32x4* __restrict__ cond,
                                             f32x4* __restrict__ out) {
    const int bstep = N_DIM * (D_DIM / 4);                  // 4,194,304 float4
    const int i = blockIdx.x * blockDim.x + threadIdx.x;    // n*64 + d4
    // wave-uniform row index -> scalar register -> s_load on lgkmcnt path
    const int n = __builtin_amdgcn_readfirstlane(i >> 6);
    const int r = rid[n];               // s_load: issues first, off vmcnt
    const f32x4 c0 = __builtin_nontemporal_load(&canvas[i]);
    const f32x4 c1 = __builtin_nontemporal_load(&canvas[i + bstep]);
    const f32x4 c2 = __builtin_nontemporal_load(&canvas[i + 2 * bstep]);
    const f32x4 c3 = __builtin_nontemporal_load(&canvas[i + 3 * bstep]);
    const int d4 = i & 63;
    const f32x4 a = cond[r * (D_DIM / 4) + d4];  // SGPR base + lane offset, L2
    out[i]             = c0 + a;
    out[i + bstep]     = c1 + a;
    out[i + 2 * bstep] = c2 + a;
    out[i + 3 * bstep] = c3 + a;
}

// ---------------------------------------------------------------------------
extern "C" void kernel_launch(void* const* d_in, const int* in_sizes, int n_in,
                              void* d_out, int out_size, void* d_ws, size_t ws_size,
                              hipStream_t stream) {
    const float* canvas = (const float*)d_in[0];  // [B,N,D]
    const float* emb    = (const float*)d_in[1];  // [R,E]
    const float* W      = (const float*)d_in[2];  // [D,E]
    const float* res    = (const float*)d_in[3];  // [R,D]
    const int*   rid    = (const int*)d_in[4];    // [N]

    // ws layout: part (KS*R*D fp32 = 4 MB) | cond (R*D fp32 = 0.5 MB)
    float* part = (float*)d_ws;
    float* cond = part + (size_t)KS * R_DIM * D_DIM;

    dim3 cgrid(R_DIM / RPB, KS);
    k_cond_direct<<<cgrid, 256, 0, stream>>>(emb, W, part);
    k_reduce<<<(R_DIM * D_DIM) / 256, 256, 0, stream>>>(part, res, cond);
    k_add<<<16384, 256, 0, stream>>>((const f32x4*)canvas, rid,
                                     (const f32x4*)cond, (f32x4*)d_out);
}